// Round 4
// baseline (1713.041 us; speedup 1.0000x reference)
//
#include <hip/hip_runtime.h>
#include <hip/hip_bf16.h>

typedef __bf16 bf16_t;
typedef __bf16 bf16x8 __attribute__((ext_vector_type(8)));
typedef float f32x4 __attribute__((ext_vector_type(4)));

#define DI __device__ __forceinline__

static constexpr int TOK = 131072;  // 32 batches * 64*64 tokens
static constexpr int NWIN = 2048;   // 32 * 64 windows

// window-order token t -> source image token (LN1 gather) == proj scatter dest.
DI int src_token(int t) {
  int b = t >> 12;
  int widx = (t >> 6) & 63;
  int n = t & 63;
  int wh = widx >> 3, ww = widx & 7;
  int i = n >> 3, j = n & 7;
  int y = ((wh << 3) + i + 4) & 63;
  int x2 = ((ww << 3) + j + 4) & 63;
  return (b << 12) + (y << 6) + x2;
}

DI f32x4 mfma16(bf16x8 a, bf16x8 b, f32x4 c) {
  return __builtin_amdgcn_mfma_f32_16x16x32_bf16(a, b, c, 0, 0, 0);
}

DI void gload_lds16(const bf16_t* g, bf16_t* l) {
  __builtin_amdgcn_global_load_lds(
      (__attribute__((address_space(1))) void*)const_cast<bf16_t*>(g),
      (__attribute__((address_space(3))) void*)l, 16, 0, 0);
}

// ---------------- weight transpose+convert: w[K][N] f32 -> wt[N][K] bf16 ----
__global__ void wconv_kernel(const float* __restrict__ w, bf16_t* __restrict__ wt,
                             int K, int N) {
  int idx = blockIdx.x * 256 + threadIdx.x;
  if (idx >= N * K) return;
  int n = idx / K, k = idx - n * K;
  wt[idx] = (bf16_t)w[(size_t)k * N + n];
}

// ---------------- LayerNorm1 + shift/partition gather, f32 -> bf16 ----------
__global__ __launch_bounds__(256)
void ln_kernel(const float* __restrict__ xin, const float* __restrict__ g,
               const float* __restrict__ be, bf16_t* __restrict__ out) {
  int w = threadIdx.x >> 6, l = threadIdx.x & 63;
  int t = blockIdx.x * 4 + w;
  int s = src_token(t);
  const float* row = xin + (size_t)s * 384;
  float v[6], s1 = 0.f, s2 = 0.f;
#pragma unroll
  for (int i = 0; i < 6; i++) {
    v[i] = row[l + i * 64];
    s1 += v[i];
    s2 += v[i] * v[i];
  }
#pragma unroll
  for (int o = 32; o; o >>= 1) {
    s1 += __shfl_xor(s1, o);
    s2 += __shfl_xor(s2, o);
  }
  float mean = s1 * (1.f / 384.f);
  float var = s2 * (1.f / 384.f) - mean * mean;
  float rs = rsqrtf(var + 1e-5f);
  bf16_t* orow = out + (size_t)t * 384;
#pragma unroll
  for (int i = 0; i < 6; i++) {
    int idx = l + i * 64;
    orow[idx] = (bf16_t)((v[i] - mean) * rs * g[idx] + be[idx]);
  }
}

// ---------------- strip GEMM: C[128 rows][384 cols] = A*Wt^T + bias ----------
// 512 threads = 8 waves (2 row-groups x 4 col-groups); single-buffered LDS.
// MODE 0: bf16 out (QKV).  MODE 1: bf16 gelu(out) (FC1).
// MODE 2: proj — x1 = val+resid, scatter to outf (image order), then fused
//         LN2 over the full 384-wide row -> lnout bf16 (window order).
// MODE 3: FC2 — outf[img] = val + resid[img] (in-place final).
template <int MODE>
__global__ __launch_bounds__(512, 2)
void gemm_strip(const bf16_t* __restrict__ A, const bf16_t* __restrict__ Wt,
                const float* __restrict__ bias, int K, int ldout,
                bf16_t* outb, float* outf, const float* resid,
                const float* g2, const float* b2, bf16_t* lnout) {
  __shared__ __align__(16) bf16_t Alds[128 * 32];
  __shared__ __align__(16) bf16_t Blds[384 * 32];
  __shared__ float lnred[128][8];
  const int tid = threadIdx.x;
  const int l = tid & 63, w = tid >> 6;
  const int lr = l & 15, lq = l >> 4;
  const int bn = blockIdx.x, bm = blockIdx.y;
  const int wr = w >> 2, wc = w & 3;
  const size_t rowA0 = (size_t)bm * 128, rowB0 = (size_t)bn * 384;

  f32x4 acc[4][6] = {};
  for (int k0 = 0; k0 < K; k0 += 32) {
    {
      int offb = w * 512;  // wave-uniform LDS base (elements)
      int off = offb + l * 8;
      gload_lds16(A + (rowA0 + (off >> 5)) * K + k0 + (off & 31), &Alds[offb]);
    }
#pragma unroll
    for (int p = 0; p < 3; p++) {
      int offb = p * 4096 + w * 512;
      int off = offb + l * 8;
      gload_lds16(Wt + (rowB0 + (off >> 5)) * K + k0 + (off & 31), &Blds[offb]);
    }
    __syncthreads();
    bf16x8 af[4], bfr[6];
#pragma unroll
    for (int fi = 0; fi < 4; fi++)
      af[fi] = *(const bf16x8*)&Alds[(wr * 64 + fi * 16 + lr) * 32 + lq * 8];
#pragma unroll
    for (int fj = 0; fj < 6; fj++)
      bfr[fj] = *(const bf16x8*)&Blds[(wc * 96 + fj * 16 + lr) * 32 + lq * 8];
#pragma unroll
    for (int fi = 0; fi < 4; fi++)
#pragma unroll
      for (int fj = 0; fj < 6; fj++)
        acc[fi][fj] = mfma16(af[fi], bfr[fj], acc[fi][fj]);
    __syncthreads();
  }

  // ---- epilogue ----
#pragma unroll
  for (int fi = 0; fi < 4; fi++) {
#pragma unroll
    for (int reg = 0; reg < 4; reg++) {
      int lrow = wr * 64 + fi * 16 + lq * 4 + reg;
      int grow = bm * 128 + lrow;
      if constexpr (MODE == 0 || MODE == 1) {
        size_t rbase = (size_t)grow * ldout;
#pragma unroll
        for (int fj = 0; fj < 6; fj++) {
          int gcol = bn * 384 + wc * 96 + fj * 16 + lr;
          float val = acc[fi][fj][reg] + bias[gcol];
          if constexpr (MODE == 1)
            val = 0.5f * val * (1.f + erff(val * 0.70710678118f));
          outb[rbase + gcol] = (bf16_t)val;
        }
      } else if constexpr (MODE == 2) {
        size_t obase = (size_t)src_token(grow) * 384;
        float s1 = 0.f, s2 = 0.f;
#pragma unroll
        for (int fj = 0; fj < 6; fj++) {
          int c = wc * 96 + fj * 16 + lr;
          float x1 = acc[fi][fj][reg] + bias[c] + resid[obase + c];
          outf[obase + c] = x1;
          acc[fi][fj][reg] = x1;  // keep for LN2, no extra regs
          s1 += x1;
          s2 += x1 * x1;
        }
#pragma unroll
        for (int o = 1; o < 16; o <<= 1) {
          s1 += __shfl_xor(s1, o);
          s2 += __shfl_xor(s2, o);
        }
        if (lr == 0) {
          lnred[lrow][wc * 2] = s1;
          lnred[lrow][wc * 2 + 1] = s2;
        }
      } else {  // MODE 3
        size_t obase = (size_t)src_token(grow) * 384;
#pragma unroll
        for (int fj = 0; fj < 6; fj++) {
          int c = wc * 96 + fj * 16 + lr;
          outf[obase + c] = acc[fi][fj][reg] + bias[c] + resid[obase + c];
        }
      }
    }
  }
  if constexpr (MODE == 2) {
    __syncthreads();
#pragma unroll
    for (int fi = 0; fi < 4; fi++) {
#pragma unroll
      for (int reg = 0; reg < 4; reg++) {
        int lrow = wr * 64 + fi * 16 + lq * 4 + reg;
        int grow = bm * 128 + lrow;
        float m = (lnred[lrow][0] + lnred[lrow][2] + lnred[lrow][4] + lnred[lrow][6]) * (1.f / 384.f);
        float v = (lnred[lrow][1] + lnred[lrow][3] + lnred[lrow][5] + lnred[lrow][7]) * (1.f / 384.f) - m * m;
        float rs = rsqrtf(v + 1e-5f);
#pragma unroll
        for (int fj = 0; fj < 6; fj++) {
          int c = wc * 96 + fj * 16 + lr;
          lnout[(size_t)grow * 384 + c] =
              (bf16_t)((acc[fi][fj][reg] - m) * rs * g2[c] + b2[c]);
        }
      }
    }
  }
}

// ---------------- per-(window, head) attention (staged, swizzled) -----------
__global__ __launch_bounds__(64)
void attn_kernel(const bf16_t* __restrict__ qkv, const float* __restrict__ btab,
                 bf16_t* __restrict__ aout) {
  __shared__ __align__(16) bf16_t Qs[64 * 32];
  __shared__ __align__(16) bf16_t Ks[64 * 32];
  __shared__ __align__(16) bf16_t Vt[32 * 64];
  __shared__ __align__(16) bf16_t Ps[64 * 64];
  const int win = blockIdx.x, h = blockIdx.y;
  const int l = threadIdx.x, lr = l & 15, lq = l >> 4;

  {
    const bf16_t* qrow = qkv + ((size_t)win * 64 + l) * 1152 + h * 32;
#pragma unroll
    for (int c = 0; c < 4; c++) {
      *(bf16x8*)&Qs[l * 32 + c * 8] = *(const bf16x8*)&qrow[c * 8];
      *(bf16x8*)&Ks[l * 32 + c * 8] = *(const bf16x8*)&qrow[384 + c * 8];
    }
#pragma unroll
    for (int c = 0; c < 4; c++) {
      bf16x8 tv = *(const bf16x8*)&qrow[768 + c * 8];
#pragma unroll
      for (int e = 0; e < 8; e++) {
        int vr = c * 8 + e;
        Vt[vr * 64 + (l ^ ((vr & 7) << 3))] = tv[e];  // swizzled col
      }
    }
  }
  __syncthreads();

  // S = Q K^T  (64x64, K=32)
  f32x4 sacc[4][4] = {};
  {
    bf16x8 a[4], b[4];
#pragma unroll
    for (int fi = 0; fi < 4; fi++)
      a[fi] = *(const bf16x8*)&Qs[(fi * 16 + lr) * 32 + lq * 8];
#pragma unroll
    for (int fj = 0; fj < 4; fj++)
      b[fj] = *(const bf16x8*)&Ks[(fj * 16 + lr) * 32 + lq * 8];
#pragma unroll
    for (int fi = 0; fi < 4; fi++)
#pragma unroll
      for (int fj = 0; fj < 4; fj++)
        sacc[fi][fj] = mfma16(a[fi], b[fj], sacc[fi][fj]);
  }

  const int widx = win & 63;
  const int wh = widx >> 3, ww = widx & 7;
  const float scale = 0.17677669529663687f;  // 32^-0.5
#pragma unroll
  for (int fi = 0; fi < 4; fi++) {
#pragma unroll
    for (int reg = 0; reg < 4; reg++) {
      int row = fi * 16 + lq * 4 + reg;  // C/D: row=(l>>4)*4+reg (+fi*16)
      int i1 = row >> 3, j1 = row & 7;
      int ly1 = (wh == 7) ? (i1 >= 4 ? 2 : 1) : 0;
      int lx1 = (ww == 7) ? (j1 >= 4 ? 2 : 1) : 0;
      float vals[4], m = -1e30f;
#pragma unroll
      for (int fj = 0; fj < 4; fj++) {
        int col = fj * 16 + lr;  // C/D: col=l&15 (+fj*16)
        int i2 = col >> 3, j2 = col & 7;
        float v = sacc[fi][fj][reg] * scale +
                  btab[((i1 - i2 + 7) * 15 + (j1 - j2 + 7)) * 12 + h];
        int ly2 = (wh == 7) ? (i2 >= 4 ? 2 : 1) : 0;
        int lx2 = (ww == 7) ? (j2 >= 4 ? 2 : 1) : 0;
        if (ly1 != ly2 || lx1 != lx2) v -= 100.f;
        vals[fj] = v;
        m = fmaxf(m, v);
      }
#pragma unroll
      for (int o = 1; o < 16; o <<= 1) m = fmaxf(m, __shfl_xor(m, o));
      float ssum = 0.f;
#pragma unroll
      for (int fj = 0; fj < 4; fj++) {
        vals[fj] = __expf(vals[fj] - m);
        ssum += vals[fj];
      }
#pragma unroll
      for (int o = 1; o < 16; o <<= 1) ssum += __shfl_xor(ssum, o);
      float inv = 1.f / ssum;
      int sw = (row & 7) << 3;
#pragma unroll
      for (int fj = 0; fj < 4; fj++)
        Ps[row * 64 + ((fj * 16 + lr) ^ sw)] = (bf16_t)(vals[fj] * inv);
    }
  }
  __syncthreads();

  // O = P V  (64x32, K=64); swizzled Ps / Vt reads (conflict-free)
  f32x4 oacc[4][2] = {};
#pragma unroll
  for (int kc = 0; kc < 2; kc++) {
    bf16x8 pa[4], vb[2];
#pragma unroll
    for (int fi = 0; fi < 4; fi++) {
      int row = fi * 16 + lr;
      pa[fi] = *(const bf16x8*)&Ps[row * 64 + ((kc * 32 + lq * 8) ^ ((row & 7) << 3))];
    }
#pragma unroll
    for (int fj = 0; fj < 2; fj++) {
      int row = fj * 16 + lr;
      vb[fj] = *(const bf16x8*)&Vt[row * 64 + ((kc * 32 + lq * 8) ^ ((row & 7) << 3))];
    }
#pragma unroll
    for (int fi = 0; fi < 4; fi++)
#pragma unroll
      for (int fj = 0; fj < 2; fj++)
        oacc[fi][fj] = mfma16(pa[fi], vb[fj], oacc[fi][fj]);
  }
#pragma unroll
  for (int fi = 0; fi < 4; fi++)
#pragma unroll
    for (int reg = 0; reg < 4; reg++) {
      int row = fi * 16 + lq * 4 + reg;
      size_t rb = ((size_t)win * 64 + row) * 384 + h * 32;
#pragma unroll
      for (int fj = 0; fj < 2; fj++)
        aout[rb + fj * 16 + lr] = (bf16_t)oacc[fi][fj][reg];
    }
}

// ---------------------------------------------------------------------------
extern "C" void kernel_launch(void* const* d_in, const int* in_sizes, int n_in,
                              void* d_out, int out_size, void* d_ws, size_t ws_size,
                              hipStream_t stream) {
  (void)in_sizes; (void)n_in; (void)out_size; (void)ws_size;
  const float* x      = (const float*)d_in[0];
  const float* gamma1 = (const float*)d_in[1];
  const float* beta1  = (const float*)d_in[2];
  const float* w_qkv  = (const float*)d_in[3];
  const float* b_qkv  = (const float*)d_in[4];
  const float* btab   = (const float*)d_in[5];
  const float* w_proj = (const float*)d_in[6];
  const float* b_proj = (const float*)d_in[7];
  const float* gamma2 = (const float*)d_in[8];
  const float* beta2  = (const float*)d_in[9];
  const float* w_fc1  = (const float*)d_in[10];
  const float* b_fc1  = (const float*)d_in[11];
  const float* w_fc2  = (const float*)d_in[12];
  const float* b_fc2  = (const float*)d_in[13];
  float* out = (float*)d_out;

  char* ws = (char*)d_ws;
  size_t off = 0;
  auto alloc = [&](size_t bytes) {
    void* p = ws + off;
    off += (bytes + 255) & ~(size_t)255;
    return p;
  };
  bf16_t* wqkvT  = (bf16_t*)alloc((size_t)1152 * 384 * 2);
  bf16_t* wprojT = (bf16_t*)alloc((size_t)384 * 384 * 2);
  bf16_t* wfc1T  = (bf16_t*)alloc((size_t)1536 * 384 * 2);
  bf16_t* wfc2T  = (bf16_t*)alloc((size_t)384 * 1536 * 2);
  // big region: qkv rows [TOK][1152] alias mlp hidden [TOK][1536] (disjoint
  // lifetimes: qkv = QKV-GEMM..attn; hidden = FC1..FC2). ~508 MB total ws.
  char* big = (char*)alloc((size_t)TOK * 1536 * 2);
  bf16_t* bufA = (bf16_t*)big;  // qkv rows
  bf16_t* bufH = (bf16_t*)big;  // mlp hidden
  bf16_t* bufB = (bf16_t*)alloc((size_t)TOK * 384 * 2);  // ln1/attn/ln2 rows

  wconv_kernel<<<(1152 * 384 + 255) / 256, 256, 0, stream>>>(w_qkv, wqkvT, 384, 1152);
  wconv_kernel<<<(384 * 384 + 255) / 256, 256, 0, stream>>>(w_proj, wprojT, 384, 384);
  wconv_kernel<<<(384 * 1536 + 255) / 256, 256, 0, stream>>>(w_fc1, wfc1T, 384, 1536);
  wconv_kernel<<<(1536 * 384 + 255) / 256, 256, 0, stream>>>(w_fc2, wfc2T, 1536, 384);

  // LN1 + roll + window partition -> bufB [131072][384] bf16
  ln_kernel<<<TOK / 4, 256, 0, stream>>>(x, gamma1, beta1, bufB);
  // QKV: 3 strips of 384 -> bufA [TOK][1152] bf16
  gemm_strip<0><<<dim3(3, TOK / 128), 512, 0, stream>>>(
      bufB, wqkvT, b_qkv, 384, 1152, bufA, nullptr, nullptr, nullptr, nullptr, nullptr);
  // windowed attention -> bufB
  attn_kernel<<<dim3(NWIN, 12), 64, 0, stream>>>(bufA, btab, bufB);
  // proj + scatter + residual(x) -> out (f32, image order), fused LN2 -> bufB
  gemm_strip<2><<<dim3(1, TOK / 128), 512, 0, stream>>>(
      bufB, wprojT, b_proj, 384, 384, nullptr, out, x, gamma2, beta2, bufB);
  // FC1 + exact GELU: 4 strips -> bufH [TOK][1536] bf16
  gemm_strip<1><<<dim3(4, TOK / 128), 512, 0, stream>>>(
      bufB, wfc1T, b_fc1, 384, 1536, bufH, nullptr, nullptr, nullptr, nullptr, nullptr);
  // FC2 + residual (in-place on out, image order)
  gemm_strip<3><<<dim3(1, TOK / 128), 512, 0, stream>>>(
      bufH, wfc2T, b_fc2, 1536, 384, nullptr, out, out, nullptr, nullptr, nullptr);
}

// Round 5
// 1248.893 us; speedup vs baseline: 1.3716x; 1.3716x over previous
//
#include <hip/hip_runtime.h>
#include <hip/hip_bf16.h>

typedef __bf16 bf16_t;
typedef __bf16 bf16x8 __attribute__((ext_vector_type(8)));
typedef float f32x4 __attribute__((ext_vector_type(4)));

#define DI __device__ __forceinline__

static constexpr int TOK = 131072;  // 32 batches * 64*64 tokens
static constexpr int NWIN = 2048;   // 32 * 64 windows

// window-order token t -> source image token (LN1 gather) == proj scatter dest.
DI int src_token(int t) {
  int b = t >> 12;
  int widx = (t >> 6) & 63;
  int n = t & 63;
  int wh = widx >> 3, ww = widx & 7;
  int i = n >> 3, j = n & 7;
  int y = ((wh << 3) + i + 4) & 63;
  int x2 = ((ww << 3) + j + 4) & 63;
  return (b << 12) + (y << 6) + x2;
}

DI f32x4 mfma16(bf16x8 a, bf16x8 b, f32x4 c) {
  return __builtin_amdgcn_mfma_f32_16x16x32_bf16(a, b, c, 0, 0, 0);
}

DI void gload_lds16(const bf16_t* g, bf16_t* l) {
  __builtin_amdgcn_global_load_lds(
      (__attribute__((address_space(1))) void*)const_cast<bf16_t*>(g),
      (__attribute__((address_space(3))) void*)l, 16, 0, 0);
}

// ---------------- weight transpose+convert: w[K][N] f32 -> wt[N][K] bf16 ----
__global__ void wconv_kernel(const float* __restrict__ w, bf16_t* __restrict__ wt,
                             int K, int N) {
  int idx = blockIdx.x * 256 + threadIdx.x;
  if (idx >= N * K) return;
  int n = idx / K, k = idx - n * K;
  wt[idx] = (bf16_t)w[(size_t)k * N + n];
}

// ---------------- LayerNorm (+optional shift/partition gather), f32 -> bf16 --
template <int MAP>
__global__ __launch_bounds__(256)
void ln_kernel(const float* __restrict__ xin, const float* __restrict__ g,
               const float* __restrict__ be, bf16_t* __restrict__ out) {
  int w = threadIdx.x >> 6, l = threadIdx.x & 63;
  int t = blockIdx.x * 4 + w;
  int s = MAP ? src_token(t) : t;
  const float* row = xin + (size_t)s * 384;
  float v[6], s1 = 0.f, s2 = 0.f;
#pragma unroll
  for (int i = 0; i < 6; i++) {
    v[i] = row[l + i * 64];
    s1 += v[i];
    s2 += v[i] * v[i];
  }
#pragma unroll
  for (int o = 32; o; o >>= 1) {
    s1 += __shfl_xor(s1, o);
    s2 += __shfl_xor(s2, o);
  }
  float mean = s1 * (1.f / 384.f);
  float var = s2 * (1.f / 384.f) - mean * mean;
  float rs = rsqrtf(var + 1e-5f);
  bf16_t* orow = out + (size_t)t * 384;
#pragma unroll
  for (int i = 0; i < 6; i++) {
    int idx = l + i * 64;
    orow[idx] = (bf16_t)((v[i] - mean) * rs * g[idx] + be[idx]);
  }
}

// ---------------- GEMM: C[M][N] = A[M][K]*Wt[N][K]^T + bias ------------------
// Round-0 proven structure (single-buffered, 2 barriers/K-step), with:
//  - BK=64 (half the barriers per K; 32 MFMA per wave between barriers)
//  - XOR slot-swizzle on LDS tiles: linear LDS dest (global_load_lds rule),
//    inverse-swizzled GLOBAL source, swizzled ds_read address (rule #21).
// MODE 0: bf16 out. 1: bf16 gelu(out). 2: f32 scatter(src_token)+resid.
// MODE 3: f32 +resid (resid aliases outf; element owned by one thread).
template <int MODE>
__global__ __launch_bounds__(256, 4)
void gemm_bt(const bf16_t* __restrict__ A, const bf16_t* __restrict__ Wt,
             const float* __restrict__ bias, int K, int ldout,
             bf16_t* outb, float* outf, const float* resid) {
  __shared__ __align__(16) bf16_t Alds[128 * 64];
  __shared__ __align__(16) bf16_t Blds[128 * 64];
  const int tid = threadIdx.x;
  const int l = tid & 63, w = tid >> 6;
  const int lr = l & 15, lq = l >> 4;
  const int bn = blockIdx.x, bm = blockIdx.y;
  const int wr = w >> 1, wc = w & 1;
  const size_t rowA0 = (size_t)bm * 128, rowB0 = (size_t)bn * 128;

  f32x4 acc[4][4] = {};
  for (int k0 = 0; k0 < K; k0 += 64) {
#pragma unroll
    for (int r = 0; r < 4; r++) {
      int offb = r * 2048 + w * 512;  // wave-uniform linear LDS base (elems)
      int off = offb + l * 8;         // this lane's linear elem offset
      int row = off >> 6;
      int slot = (off >> 3) & 7;
      int scol = (slot ^ (row & 7)) << 3;  // inverse-swizzled source column
      gload_lds16(A + (rowA0 + row) * K + k0 + scol, &Alds[offb]);
      gload_lds16(Wt + (rowB0 + row) * K + k0 + scol, &Blds[offb]);
    }
    __syncthreads();
#pragma unroll
    for (int ks = 0; ks < 2; ks++) {
      bf16x8 af[4], bfr[4];
#pragma unroll
      for (int fi = 0; fi < 4; fi++) {
        int row = wr * 64 + fi * 16 + lr;
        af[fi] = *(const bf16x8*)&Alds[row * 64 +
                                       ((ks * 32 + lq * 8) ^ ((row & 7) << 3))];
      }
#pragma unroll
      for (int fj = 0; fj < 4; fj++) {
        int row = wc * 64 + fj * 16 + lr;
        bfr[fj] = *(const bf16x8*)&Blds[row * 64 +
                                        ((ks * 32 + lq * 8) ^ ((row & 7) << 3))];
      }
#pragma unroll
      for (int fi = 0; fi < 4; fi++)
#pragma unroll
        for (int fj = 0; fj < 4; fj++)
          acc[fi][fj] = mfma16(af[fi], bfr[fj], acc[fi][fj]);
    }
    __syncthreads();
  }

#pragma unroll
  for (int fi = 0; fi < 4; fi++) {
#pragma unroll
    for (int reg = 0; reg < 4; reg++) {
      int grow = bm * 128 + wr * 64 + fi * 16 + lq * 4 + reg;
      size_t rbase;
      if constexpr (MODE == 2)
        rbase = (size_t)src_token(grow) * ldout;
      else
        rbase = (size_t)grow * ldout;
#pragma unroll
      for (int fj = 0; fj < 4; fj++) {
        int gcol = bn * 128 + wc * 64 + fj * 16 + lr;
        float val = acc[fi][fj][reg] + bias[gcol];
        if constexpr (MODE == 0) {
          outb[rbase + gcol] = (bf16_t)val;
        } else if constexpr (MODE == 1) {
          val = 0.5f * val * (1.f + erff(val * 0.70710678118f));
          outb[rbase + gcol] = (bf16_t)val;
        } else {
          outf[rbase + gcol] = val + resid[rbase + gcol];
        }
      }
    }
  }
}

// ---------------- per-(window, head) attention (staged, swizzled) -----------
__global__ __launch_bounds__(64)
void attn_kernel(const bf16_t* __restrict__ qkv, const float* __restrict__ btab,
                 bf16_t* __restrict__ aout) {
  __shared__ __align__(16) bf16_t Qs[64 * 32];
  __shared__ __align__(16) bf16_t Ks[64 * 32];
  __shared__ __align__(16) bf16_t Vt[32 * 64];
  __shared__ __align__(16) bf16_t Ps[64 * 64];
  const int win = blockIdx.x, h = blockIdx.y;
  const int l = threadIdx.x, lr = l & 15, lq = l >> 4;

  {
    const bf16_t* qrow = qkv + ((size_t)win * 64 + l) * 1152 + h * 32;
#pragma unroll
    for (int c = 0; c < 4; c++) {
      *(bf16x8*)&Qs[l * 32 + c * 8] = *(const bf16x8*)&qrow[c * 8];
      *(bf16x8*)&Ks[l * 32 + c * 8] = *(const bf16x8*)&qrow[384 + c * 8];
    }
#pragma unroll
    for (int c = 0; c < 4; c++) {
      bf16x8 tv = *(const bf16x8*)&qrow[768 + c * 8];
#pragma unroll
      for (int e = 0; e < 8; e++) {
        int vr = c * 8 + e;
        Vt[vr * 64 + (l ^ ((vr & 7) << 3))] = tv[e];  // swizzled col
      }
    }
  }
  __syncthreads();

  // S = Q K^T  (64x64, K=32)
  f32x4 sacc[4][4] = {};
  {
    bf16x8 a[4], b[4];
#pragma unroll
    for (int fi = 0; fi < 4; fi++)
      a[fi] = *(const bf16x8*)&Qs[(fi * 16 + lr) * 32 + lq * 8];
#pragma unroll
    for (int fj = 0; fj < 4; fj++)
      b[fj] = *(const bf16x8*)&Ks[(fj * 16 + lr) * 32 + lq * 8];
#pragma unroll
    for (int fi = 0; fi < 4; fi++)
#pragma unroll
      for (int fj = 0; fj < 4; fj++)
        sacc[fi][fj] = mfma16(a[fi], b[fj], sacc[fi][fj]);
  }

  const int widx = win & 63;
  const int wh = widx >> 3, ww = widx & 7;
  const float scale = 0.17677669529663687f;  // 32^-0.5
#pragma unroll
  for (int fi = 0; fi < 4; fi++) {
#pragma unroll
    for (int reg = 0; reg < 4; reg++) {
      int row = fi * 16 + lq * 4 + reg;  // C/D: row=(l>>4)*4+reg (+fi*16)
      int i1 = row >> 3, j1 = row & 7;
      int ly1 = (wh == 7) ? (i1 >= 4 ? 2 : 1) : 0;
      int lx1 = (ww == 7) ? (j1 >= 4 ? 2 : 1) : 0;
      float vals[4], m = -1e30f;
#pragma unroll
      for (int fj = 0; fj < 4; fj++) {
        int col = fj * 16 + lr;  // C/D: col=l&15 (+fj*16)
        int i2 = col >> 3, j2 = col & 7;
        float v = sacc[fi][fj][reg] * scale +
                  btab[((i1 - i2 + 7) * 15 + (j1 - j2 + 7)) * 12 + h];
        int ly2 = (wh == 7) ? (i2 >= 4 ? 2 : 1) : 0;
        int lx2 = (ww == 7) ? (j2 >= 4 ? 2 : 1) : 0;
        if (ly1 != ly2 || lx1 != lx2) v -= 100.f;
        vals[fj] = v;
        m = fmaxf(m, v);
      }
#pragma unroll
      for (int o = 1; o < 16; o <<= 1) m = fmaxf(m, __shfl_xor(m, o));
      float ssum = 0.f;
#pragma unroll
      for (int fj = 0; fj < 4; fj++) {
        vals[fj] = __expf(vals[fj] - m);
        ssum += vals[fj];
      }
#pragma unroll
      for (int o = 1; o < 16; o <<= 1) ssum += __shfl_xor(ssum, o);
      float inv = 1.f / ssum;
      int sw = (row & 7) << 3;
#pragma unroll
      for (int fj = 0; fj < 4; fj++)
        Ps[row * 64 + ((fj * 16 + lr) ^ sw)] = (bf16_t)(vals[fj] * inv);
    }
  }
  __syncthreads();

  // O = P V  (64x32, K=64); swizzled Ps / Vt reads (conflict-free)
  f32x4 oacc[4][2] = {};
#pragma unroll
  for (int kc = 0; kc < 2; kc++) {
    bf16x8 pa[4], vb[2];
#pragma unroll
    for (int fi = 0; fi < 4; fi++) {
      int row = fi * 16 + lr;
      pa[fi] = *(const bf16x8*)&Ps[row * 64 + ((kc * 32 + lq * 8) ^ ((row & 7) << 3))];
    }
#pragma unroll
    for (int fj = 0; fj < 2; fj++) {
      int row = fj * 16 + lr;
      vb[fj] = *(const bf16x8*)&Vt[row * 64 + ((kc * 32 + lq * 8) ^ ((row & 7) << 3))];
    }
#pragma unroll
    for (int fi = 0; fi < 4; fi++)
#pragma unroll
      for (int fj = 0; fj < 2; fj++)
        oacc[fi][fj] = mfma16(pa[fi], vb[fj], oacc[fi][fj]);
  }
#pragma unroll
  for (int fi = 0; fi < 4; fi++)
#pragma unroll
    for (int reg = 0; reg < 4; reg++) {
      int row = fi * 16 + lq * 4 + reg;
      size_t rb = ((size_t)win * 64 + row) * 384 + h * 32;
#pragma unroll
      for (int fj = 0; fj < 2; fj++)
        aout[rb + fj * 16 + lr] = (bf16_t)oacc[fi][fj][reg];
    }
}

// ---------------------------------------------------------------------------
extern "C" void kernel_launch(void* const* d_in, const int* in_sizes, int n_in,
                              void* d_out, int out_size, void* d_ws, size_t ws_size,
                              hipStream_t stream) {
  (void)in_sizes; (void)n_in; (void)out_size; (void)ws_size;
  const float* x      = (const float*)d_in[0];
  const float* gamma1 = (const float*)d_in[1];
  const float* beta1  = (const float*)d_in[2];
  const float* w_qkv  = (const float*)d_in[3];
  const float* b_qkv  = (const float*)d_in[4];
  const float* btab   = (const float*)d_in[5];
  const float* w_proj = (const float*)d_in[6];
  const float* b_proj = (const float*)d_in[7];
  const float* gamma2 = (const float*)d_in[8];
  const float* beta2  = (const float*)d_in[9];
  const float* w_fc1  = (const float*)d_in[10];
  const float* b_fc1  = (const float*)d_in[11];
  const float* w_fc2  = (const float*)d_in[12];
  const float* b_fc2  = (const float*)d_in[13];
  float* out = (float*)d_out;

  char* ws = (char*)d_ws;
  size_t off = 0;
  auto alloc = [&](size_t bytes) {
    void* p = ws + off;
    off += (bytes + 255) & ~(size_t)255;
    return p;
  };
  bf16_t* wqkvT  = (bf16_t*)alloc((size_t)1152 * 384 * 2);
  bf16_t* wprojT = (bf16_t*)alloc((size_t)384 * 384 * 2);
  bf16_t* wfc1T  = (bf16_t*)alloc((size_t)1536 * 384 * 2);
  bf16_t* wfc2T  = (bf16_t*)alloc((size_t)384 * 1536 * 2);
  // qkv rows [TOK][1152] alias mlp hidden [TOK][1536]; lifetimes disjoint.
  char* big = (char*)alloc((size_t)TOK * 1536 * 2);
  bf16_t* bufA = (bf16_t*)big;  // qkv rows
  bf16_t* bufH = (bf16_t*)big;  // mlp hidden
  bf16_t* bufB = (bf16_t*)alloc((size_t)TOK * 384 * 2);  // ln1/attn/ln2 rows

  wconv_kernel<<<(1152 * 384 + 255) / 256, 256, 0, stream>>>(w_qkv, wqkvT, 384, 1152);
  wconv_kernel<<<(384 * 384 + 255) / 256, 256, 0, stream>>>(w_proj, wprojT, 384, 384);
  wconv_kernel<<<(384 * 1536 + 255) / 256, 256, 0, stream>>>(w_fc1, wfc1T, 384, 1536);
  wconv_kernel<<<(1536 * 384 + 255) / 256, 256, 0, stream>>>(w_fc2, wfc2T, 1536, 384);

  // LN1 + roll + window partition -> bufB [131072][384] bf16
  ln_kernel<1><<<TOK / 4, 256, 0, stream>>>(x, gamma1, beta1, bufB);
  // QKV: [131072,384] x [384,1152] -> bufA bf16
  gemm_bt<0><<<dim3(1152 / 128, TOK / 128), 256, 0, stream>>>(
      bufB, wqkvT, b_qkv, 384, 1152, bufA, nullptr, nullptr);
  // windowed attention -> bufB [131072][384] bf16
  attn_kernel<<<dim3(NWIN, 12), 64, 0, stream>>>(bufA, btab, bufB);
  // proj + un-roll scatter + residual(x) -> out (x1, f32)
  gemm_bt<2><<<dim3(384 / 128, TOK / 128), 256, 0, stream>>>(
      bufB, wprojT, b_proj, 384, 384, nullptr, out, x);
  // LN2 -> bufB bf16
  ln_kernel<0><<<TOK / 4, 256, 0, stream>>>(out, gamma2, beta2, bufB);
  // FC1 + exact GELU -> bufH [131072][1536] bf16
  gemm_bt<1><<<dim3(1536 / 128, TOK / 128), 256, 0, stream>>>(
      bufB, wfc1T, b_fc1, 384, 1536, bufH, nullptr, nullptr);
  // FC2 + residual(out, in-place) -> out
  gemm_bt<3><<<dim3(384 / 128, TOK / 128), 256, 0, stream>>>(
      bufH, wfc2T, b_fc2, 1536, 384, nullptr, out, out);
}

// Round 6
// 1211.650 us; speedup vs baseline: 1.4138x; 1.0307x over previous
//
#include <hip/hip_runtime.h>
#include <hip/hip_bf16.h>

typedef __bf16 bf16_t;
typedef __bf16 bf16x8 __attribute__((ext_vector_type(8)));
typedef float f32x4 __attribute__((ext_vector_type(4)));

#define DI __device__ __forceinline__

static constexpr int TOK = 131072;  // 32 batches * 64*64 tokens
static constexpr int NWIN = 2048;   // 32 * 64 windows

// window-order token t -> source image token (LN1 gather) == proj scatter dest.
DI int src_token(int t) {
  int b = t >> 12;
  int widx = (t >> 6) & 63;
  int n = t & 63;
  int wh = widx >> 3, ww = widx & 7;
  int i = n >> 3, j = n & 7;
  int y = ((wh << 3) + i + 4) & 63;
  int x2 = ((ww << 3) + j + 4) & 63;
  return (b << 12) + (y << 6) + x2;
}

DI f32x4 mfma16(bf16x8 a, bf16x8 b, f32x4 c) {
  return __builtin_amdgcn_mfma_f32_16x16x32_bf16(a, b, c, 0, 0, 0);
}

DI void gload_lds16(const bf16_t* g, bf16_t* l) {
  __builtin_amdgcn_global_load_lds(
      (__attribute__((address_space(1))) void*)const_cast<bf16_t*>(g),
      (__attribute__((address_space(3))) void*)l, 16, 0, 0);
}

// ---------------- weight transpose+convert: w[K][N] f32 -> wt[N][K] bf16 ----
__global__ void wconv_kernel(const float* __restrict__ w, bf16_t* __restrict__ wt,
                             int K, int N) {
  int idx = blockIdx.x * 256 + threadIdx.x;
  if (idx >= N * K) return;
  int n = idx / K, k = idx - n * K;
  wt[idx] = (bf16_t)w[(size_t)k * N + n];
}

// ---------------- LayerNorm (+optional shift/partition gather), f32 -> bf16 --
template <int MAP>
__global__ __launch_bounds__(256)
void ln_kernel(const float* __restrict__ xin, const float* __restrict__ g,
               const float* __restrict__ be, bf16_t* __restrict__ out) {
  int w = threadIdx.x >> 6, l = threadIdx.x & 63;
  int t = blockIdx.x * 4 + w;
  int s = MAP ? src_token(t) : t;
  const float* row = xin + (size_t)s * 384;
  float v[6], s1 = 0.f, s2 = 0.f;
#pragma unroll
  for (int i = 0; i < 6; i++) {
    v[i] = row[l + i * 64];
    s1 += v[i];
    s2 += v[i] * v[i];
  }
#pragma unroll
  for (int o = 32; o; o >>= 1) {
    s1 += __shfl_xor(s1, o);
    s2 += __shfl_xor(s2, o);
  }
  float mean = s1 * (1.f / 384.f);
  float var = s2 * (1.f / 384.f) - mean * mean;
  float rs = rsqrtf(var + 1e-5f);
  bf16_t* orow = out + (size_t)t * 384;
#pragma unroll
  for (int i = 0; i < 6; i++) {
    int idx = l + i * 64;
    orow[idx] = (bf16_t)((v[i] - mean) * rs * g[idx] + be[idx]);
  }
}

// ---------------- GEMM: C[M][N] = A[M][K]*Wt[N][K]^T + bias ------------------
// Proven round-5 structure: single-buffered, BK=64, both-sides XOR swizzle
// (linear LDS dest + inverse-swizzled global source + swizzled ds_read).
// NEW: 1D grid + bijective XCD-chunked swizzle (T1) — each XCD owns
// contiguous row-panels so the shared A-panel is fetched once per XCD L2.
// Requires gridDim.x % 8 == 0 (all our grids: cols*1024).
// MODE 0: bf16 out. 1: bf16 gelu(out). 2: f32 scatter(src_token)+resid.
// MODE 3: f32 +resid (resid aliases outf; element owned by one thread).
template <int MODE>
__global__ __launch_bounds__(256, 4)
void gemm_bt(const bf16_t* __restrict__ A, const bf16_t* __restrict__ Wt,
             const float* __restrict__ bias, int K, int ldout, int ncols,
             bf16_t* outb, float* outf, const float* resid) {
  __shared__ __align__(16) bf16_t Alds[128 * 64];
  __shared__ __align__(16) bf16_t Blds[128 * 64];
  const int tid = threadIdx.x;
  const int l = tid & 63, w = tid >> 6;
  const int lr = l & 15, lq = l >> 4;
  // XCD-chunked bijective remap (nwg % 8 == 0)
  const int nwg = gridDim.x;
  const int orig = blockIdx.x;
  const int wgid = (orig & 7) * (nwg >> 3) + (orig >> 3);
  const int bn = wgid % ncols, bm = wgid / ncols;
  const int wr = w >> 1, wc = w & 1;
  const size_t rowA0 = (size_t)bm * 128, rowB0 = (size_t)bn * 128;

  f32x4 acc[4][4] = {};
  for (int k0 = 0; k0 < K; k0 += 64) {
#pragma unroll
    for (int r = 0; r < 4; r++) {
      int offb = r * 2048 + w * 512;  // wave-uniform linear LDS base (elems)
      int off = offb + l * 8;         // this lane's linear elem offset
      int row = off >> 6;
      int slot = (off >> 3) & 7;
      int scol = (slot ^ (row & 7)) << 3;  // inverse-swizzled source column
      gload_lds16(A + (rowA0 + row) * K + k0 + scol, &Alds[offb]);
      gload_lds16(Wt + (rowB0 + row) * K + k0 + scol, &Blds[offb]);
    }
    __syncthreads();
#pragma unroll
    for (int ks = 0; ks < 2; ks++) {
      bf16x8 af[4], bfr[4];
#pragma unroll
      for (int fi = 0; fi < 4; fi++) {
        int row = wr * 64 + fi * 16 + lr;
        af[fi] = *(const bf16x8*)&Alds[row * 64 +
                                       ((ks * 32 + lq * 8) ^ ((row & 7) << 3))];
      }
#pragma unroll
      for (int fj = 0; fj < 4; fj++) {
        int row = wc * 64 + fj * 16 + lr;
        bfr[fj] = *(const bf16x8*)&Blds[row * 64 +
                                        ((ks * 32 + lq * 8) ^ ((row & 7) << 3))];
      }
#pragma unroll
      for (int fi = 0; fi < 4; fi++)
#pragma unroll
        for (int fj = 0; fj < 4; fj++)
          acc[fi][fj] = mfma16(af[fi], bfr[fj], acc[fi][fj]);
    }
    __syncthreads();
  }

#pragma unroll
  for (int fi = 0; fi < 4; fi++) {
#pragma unroll
    for (int reg = 0; reg < 4; reg++) {
      int grow = bm * 128 + wr * 64 + fi * 16 + lq * 4 + reg;
      size_t rbase;
      if constexpr (MODE == 2)
        rbase = (size_t)src_token(grow) * ldout;
      else
        rbase = (size_t)grow * ldout;
#pragma unroll
      for (int fj = 0; fj < 4; fj++) {
        int gcol = bn * 128 + wc * 64 + fj * 16 + lr;
        float val = acc[fi][fj][reg] + bias[gcol];
        if constexpr (MODE == 0) {
          outb[rbase + gcol] = (bf16_t)val;
        } else if constexpr (MODE == 1) {
          val = 0.5f * val * (1.f + erff(val * 0.70710678118f));
          outb[rbase + gcol] = (bf16_t)val;
        } else {
          outf[rbase + gcol] = val + resid[rbase + gcol];
        }
      }
    }
  }
}

// ---------------- per-(window, head) attention (staged, swizzled) -----------
__global__ __launch_bounds__(64)
void attn_kernel(const bf16_t* __restrict__ qkv, const float* __restrict__ btab,
                 bf16_t* __restrict__ aout) {
  __shared__ __align__(16) bf16_t Qs[64 * 32];
  __shared__ __align__(16) bf16_t Ks[64 * 32];
  __shared__ __align__(16) bf16_t Vt[32 * 64];
  __shared__ __align__(16) bf16_t Ps[64 * 64];
  const int win = blockIdx.x, h = blockIdx.y;
  const int l = threadIdx.x, lr = l & 15, lq = l >> 4;

  {
    const bf16_t* qrow = qkv + ((size_t)win * 64 + l) * 1152 + h * 32;
#pragma unroll
    for (int c = 0; c < 4; c++) {
      *(bf16x8*)&Qs[l * 32 + c * 8] = *(const bf16x8*)&qrow[c * 8];
      *(bf16x8*)&Ks[l * 32 + c * 8] = *(const bf16x8*)&qrow[384 + c * 8];
    }
#pragma unroll
    for (int c = 0; c < 4; c++) {
      bf16x8 tv = *(const bf16x8*)&qrow[768 + c * 8];
#pragma unroll
      for (int e = 0; e < 8; e++) {
        int vr = c * 8 + e;
        Vt[vr * 64 + (l ^ ((vr & 7) << 3))] = tv[e];  // swizzled col
      }
    }
  }
  __syncthreads();

  // S = Q K^T  (64x64, K=32)
  f32x4 sacc[4][4] = {};
  {
    bf16x8 a[4], b[4];
#pragma unroll
    for (int fi = 0; fi < 4; fi++)
      a[fi] = *(const bf16x8*)&Qs[(fi * 16 + lr) * 32 + lq * 8];
#pragma unroll
    for (int fj = 0; fj < 4; fj++)
      b[fj] = *(const bf16x8*)&Ks[(fj * 16 + lr) * 32 + lq * 8];
#pragma unroll
    for (int fi = 0; fi < 4; fi++)
#pragma unroll
      for (int fj = 0; fj < 4; fj++)
        sacc[fi][fj] = mfma16(a[fi], b[fj], sacc[fi][fj]);
  }

  const int widx = win & 63;
  const int wh = widx >> 3, ww = widx & 7;
  const float scale = 0.17677669529663687f;  // 32^-0.5
#pragma unroll
  for (int fi = 0; fi < 4; fi++) {
#pragma unroll
    for (int reg = 0; reg < 4; reg++) {
      int row = fi * 16 + lq * 4 + reg;  // C/D: row=(l>>4)*4+reg (+fi*16)
      int i1 = row >> 3, j1 = row & 7;
      int ly1 = (wh == 7) ? (i1 >= 4 ? 2 : 1) : 0;
      int lx1 = (ww == 7) ? (j1 >= 4 ? 2 : 1) : 0;
      float vals[4], m = -1e30f;
#pragma unroll
      for (int fj = 0; fj < 4; fj++) {
        int col = fj * 16 + lr;  // C/D: col=l&15 (+fj*16)
        int i2 = col >> 3, j2 = col & 7;
        float v = sacc[fi][fj][reg] * scale +
                  btab[((i1 - i2 + 7) * 15 + (j1 - j2 + 7)) * 12 + h];
        int ly2 = (wh == 7) ? (i2 >= 4 ? 2 : 1) : 0;
        int lx2 = (ww == 7) ? (j2 >= 4 ? 2 : 1) : 0;
        if (ly1 != ly2 || lx1 != lx2) v -= 100.f;
        vals[fj] = v;
        m = fmaxf(m, v);
      }
#pragma unroll
      for (int o = 1; o < 16; o <<= 1) m = fmaxf(m, __shfl_xor(m, o));
      float ssum = 0.f;
#pragma unroll
      for (int fj = 0; fj < 4; fj++) {
        vals[fj] = __expf(vals[fj] - m);
        ssum += vals[fj];
      }
#pragma unroll
      for (int o = 1; o < 16; o <<= 1) ssum += __shfl_xor(ssum, o);
      float inv = 1.f / ssum;
      int sw = (row & 7) << 3;
#pragma unroll
      for (int fj = 0; fj < 4; fj++)
        Ps[row * 64 + ((fj * 16 + lr) ^ sw)] = (bf16_t)(vals[fj] * inv);
    }
  }
  __syncthreads();

  // O = P V  (64x32, K=64); swizzled Ps / Vt reads (conflict-free)
  f32x4 oacc[4][2] = {};
#pragma unroll
  for (int kc = 0; kc < 2; kc++) {
    bf16x8 pa[4], vb[2];
#pragma unroll
    for (int fi = 0; fi < 4; fi++) {
      int row = fi * 16 + lr;
      pa[fi] = *(const bf16x8*)&Ps[row * 64 + ((kc * 32 + lq * 8) ^ ((row & 7) << 3))];
    }
#pragma unroll
    for (int fj = 0; fj < 2; fj++) {
      int row = fj * 16 + lr;
      vb[fj] = *(const bf16x8*)&Vt[row * 64 + ((kc * 32 + lq * 8) ^ ((row & 7) << 3))];
    }
#pragma unroll
    for (int fi = 0; fi < 4; fi++)
#pragma unroll
      for (int fj = 0; fj < 2; fj++)
        oacc[fi][fj] = mfma16(pa[fi], vb[fj], oacc[fi][fj]);
  }
#pragma unroll
  for (int fi = 0; fi < 4; fi++)
#pragma unroll
    for (int reg = 0; reg < 4; reg++) {
      int row = fi * 16 + lq * 4 + reg;
      size_t rb = ((size_t)win * 64 + row) * 384 + h * 32;
#pragma unroll
      for (int fj = 0; fj < 2; fj++)
        aout[rb + fj * 16 + lr] = (bf16_t)oacc[fi][fj][reg];
    }
}

// ---------------------------------------------------------------------------
extern "C" void kernel_launch(void* const* d_in, const int* in_sizes, int n_in,
                              void* d_out, int out_size, void* d_ws, size_t ws_size,
                              hipStream_t stream) {
  (void)in_sizes; (void)n_in; (void)out_size; (void)ws_size;
  const float* x      = (const float*)d_in[0];
  const float* gamma1 = (const float*)d_in[1];
  const float* beta1  = (const float*)d_in[2];
  const float* w_qkv  = (const float*)d_in[3];
  const float* b_qkv  = (const float*)d_in[4];
  const float* btab   = (const float*)d_in[5];
  const float* w_proj = (const float*)d_in[6];
  const float* b_proj = (const float*)d_in[7];
  const float* gamma2 = (const float*)d_in[8];
  const float* beta2  = (const float*)d_in[9];
  const float* w_fc1  = (const float*)d_in[10];
  const float* b_fc1  = (const float*)d_in[11];
  const float* w_fc2  = (const float*)d_in[12];
  const float* b_fc2  = (const float*)d_in[13];
  float* out = (float*)d_out;

  char* ws = (char*)d_ws;
  size_t off = 0;
  auto alloc = [&](size_t bytes) {
    void* p = ws + off;
    off += (bytes + 255) & ~(size_t)255;
    return p;
  };
  bf16_t* wqkvT  = (bf16_t*)alloc((size_t)1152 * 384 * 2);
  bf16_t* wprojT = (bf16_t*)alloc((size_t)384 * 384 * 2);
  bf16_t* wfc1T  = (bf16_t*)alloc((size_t)1536 * 384 * 2);
  bf16_t* wfc2T  = (bf16_t*)alloc((size_t)384 * 1536 * 2);
  // qkv rows [TOK][1152] alias mlp hidden [TOK][1536]; lifetimes disjoint.
  char* big = (char*)alloc((size_t)TOK * 1536 * 2);
  bf16_t* bufA = (bf16_t*)big;  // qkv rows
  bf16_t* bufH = (bf16_t*)big;  // mlp hidden
  bf16_t* bufB = (bf16_t*)alloc((size_t)TOK * 384 * 2);  // ln1/attn/ln2 rows

  wconv_kernel<<<(1152 * 384 + 255) / 256, 256, 0, stream>>>(w_qkv, wqkvT, 384, 1152);
  wconv_kernel<<<(384 * 384 + 255) / 256, 256, 0, stream>>>(w_proj, wprojT, 384, 384);
  wconv_kernel<<<(384 * 1536 + 255) / 256, 256, 0, stream>>>(w_fc1, wfc1T, 384, 1536);
  wconv_kernel<<<(1536 * 384 + 255) / 256, 256, 0, stream>>>(w_fc2, wfc2T, 1536, 384);

  // LN1 + roll + window partition -> bufB [131072][384] bf16
  ln_kernel<1><<<TOK / 4, 256, 0, stream>>>(x, gamma1, beta1, bufB);
  // QKV: [131072,384] x [384,1152] -> bufA bf16   (grid 9*1024, %8==0)
  gemm_bt<0><<<9 * (TOK / 128), 256, 0, stream>>>(
      bufB, wqkvT, b_qkv, 384, 1152, 9, bufA, nullptr, nullptr);
  // windowed attention -> bufB [131072][384] bf16
  attn_kernel<<<dim3(NWIN, 12), 64, 0, stream>>>(bufA, btab, bufB);
  // proj + un-roll scatter + residual(x) -> out (x1, f32)  (grid 3*1024)
  gemm_bt<2><<<3 * (TOK / 128), 256, 0, stream>>>(
      bufB, wprojT, b_proj, 384, 384, 3, nullptr, out, x);
  // LN2 -> bufB bf16
  ln_kernel<0><<<TOK / 4, 256, 0, stream>>>(out, gamma2, beta2, bufB);
  // FC1 + exact GELU -> bufH [131072][1536] bf16  (grid 12*1024)
  gemm_bt<1><<<12 * (TOK / 128), 256, 0, stream>>>(
      bufB, wfc1T, b_fc1, 384, 1536, 12, bufH, nullptr, nullptr);
  // FC2 + residual(out, in-place) -> out  (grid 3*1024)
  gemm_bt<3><<<3 * (TOK / 128), 256, 0, stream>>>(
      bufH, wfc2T, b_fc2, 1536, 384, 3, nullptr, out, out);
}